// Round 9
// baseline (266.571 us; speedup 1.0000x reference)
//
#include <hip/hip_runtime.h>
#include <math.h>

#define NV 778
#define NJ 16
#define NCOMP 24
#define NBETA 10
#define FC 1554
#define NA 32
#define NB 8
#define NOBJ 16384
#define VD (NV*3)          // 2334
#define BCH 584            // ceil(VD/4) row-chunks per batch for k_blend
#define NVQ 832            // padded vertex slots (104 groups of 8)
#define NG 104             // NVQ/8 groups
#define NCB 3              // extra C-blocks appended to k_blend grid

// ---------------- Kernel 1: fused pose + blendshapes + C0/C1 side-compute.
// Main blocks (proven R1 structure): VP = vt + sd*beta + pd*posefeat.
// 3 extra blocks compute C0[48] = Jreg@vt and C1[480] = Jreg@sd so k_skel
// gets joints J = C0 + C1*beta in 48 FMAs (kills its 48KB Jreg reduction).
__global__ __launch_bounds__(256) void k_blend(
    const float* __restrict__ hp, const float* __restrict__ pca,
    const float* __restrict__ vt, const float* __restrict__ sd,
    const float* __restrict__ pd, const float* __restrict__ beta,
    const float* __restrict__ Jreg,
    float* __restrict__ VP, float* __restrict__ C0, float* __restrict__ C1,
    float* __restrict__ pen)
{
    int bid = blockIdx.x;
    int t = threadIdx.x;

    if (bid >= NB*BCH) {               // ---- C-blocks: 528 dot-products of 778
        int gid = (bid - NB*BCH)*256 + t;
        if (gid < 528) {
            int jd, k;
            if (gid < 48) { jd = gid; k = -1; }
            else          { jd = (gid-48)/NBETA; k = (gid-48)%NBETA; }
            int j = jd/3, d = jd%3;
            const float* jr = Jreg + j*NV;
            float acc = 0.0f;
            for (int v = 0; v < NV; ++v) {
                float x = (k < 0) ? vt[v*3+d] : sd[(v*3+d)*NBETA + k];
                acc += jr[v] * x;
            }
            if (k < 0) C0[jd] = acc; else C1[jd*NBETA + k] = acc;
        }
        return;
    }

    int b = bid / BCH, c = bid % BCH;
    int wid = t >> 6, lane = t & 63;
    __shared__ float h45[45];
    __shared__ float sR[NJ*9];
    __shared__ float spf[135];

    if (t < 45) {
        float acc = 0.0f;
        #pragma unroll
        for (int k = 0; k < NCOMP; ++k) acc += hp[b*30 + 6 + k] * pca[k*45 + t];
        h45[t] = acc;
    }
    __syncthreads();
    if (t < NJ) {
        float rx, ry, rz;
        if (t == 0) { rx = hp[b*30+3]; ry = hp[b*30+4]; rz = hp[b*30+5]; }
        else        { rx = h45[(t-1)*3]; ry = h45[(t-1)*3+1]; rz = h45[(t-1)*3+2]; }
        float th = sqrtf(rx*rx + ry*ry + rz*rz + 1e-16f);
        float kx = rx/th, ky = ry/th, kz = rz/th;
        float cc = cosf(th), s = sinf(th), o = 1.0f - cc;
        float R[9];
        R[0] = cc + o*kx*kx;     R[1] = -s*kz + o*kx*ky;  R[2] =  s*ky + o*kx*kz;
        R[3] =  s*kz + o*ky*kx;  R[4] = cc + o*ky*ky;     R[5] = -s*kx + o*ky*kz;
        R[6] = -s*ky + o*kz*kx;  R[7] =  s*kx + o*kz*ky;  R[8] = cc + o*kz*kz;
        #pragma unroll
        for (int i = 0; i < 9; ++i) sR[t*9+i] = R[i];
    }
    __syncthreads();
    if (t < 135) {
        int mn = t % 9;
        float d = (mn == 0 || mn == 4 || mn == 8) ? 1.0f : 0.0f;
        spf[t] = sR[9 + t] - d;
    }
    if (bid == 0 && t == 0) *pen = 0.0f;
    __syncthreads();

    int r = c*4 + wid;                 // row within batch: v*3 + d
    if (r < VD) {
        const float* p  = pd + r * 135;
        float accP = p[lane] * spf[lane] + p[lane+64] * spf[lane+64];
        accP += (lane < 7) ? p[lane+128] * spf[lane+128] : 0.0f;

        float accS = (lane < NBETA) ? sd[r*NBETA + lane] * beta[b*NBETA + lane] : 0.0f;

        #pragma unroll
        for (int off = 32; off; off >>= 1) {
            accP += __shfl_down(accP, off, 64);
            accS += __shfl_down(accS, off, 64);
        }
        if (lane == 0) VP[b*VD + r] = vt[r] + accS + accP;
    }
}

// ---------------- Kernel 2: skel-lite — J from C0/C1, chain, LBS, normals.
// No Jreg/VS reads (the 13-iteration global reduce is gone). 8 blocks x 256.
__global__ __launch_bounds__(256) void k_skel2(
    const float* __restrict__ hp, const float* __restrict__ pca,
    const float* __restrict__ beta,
    const float* __restrict__ C0, const float* __restrict__ C1,
    const float* __restrict__ W, const float* __restrict__ VP,
    const int* __restrict__ faces, const float* __restrict__ aw,
    const int* __restrict__ afi,
    float* __restrict__ verts, float4* __restrict__ PK,
    float* __restrict__ NRM, float* __restrict__ contact)
{
    int b = blockIdx.x, t = threadIdx.x;
    __shared__ float h45[45];
    __shared__ float sR[NJ*9];
    __shared__ float sJ[NJ*3];
    __shared__ float4 sA4[NJ*3];
    __shared__ float sv[VD];
    __shared__ float sn[VD];

    // phase 1: PCA matvec + LDS init + PK sentinels
    if (t < 45) {
        float acc = 0.0f;
        #pragma unroll
        for (int k = 0; k < NCOMP; ++k) acc += hp[b*30 + 6 + k] * pca[k*45 + t];
        h45[t] = acc;
    }
    for (int i = t; i < VD; i += 256) sn[i] = 0.0f;
    if (t < NVQ - NV) PK[b*NVQ + NV + t] = make_float4(0.f, 0.f, 0.f, 1e30f);
    __syncthreads();

    // phase 2: Rodrigues (wave 0) + joints from C0/C1 (wave 1)
    if (t < NJ) {
        float rx, ry, rz;
        if (t == 0) { rx = hp[b*30+3]; ry = hp[b*30+4]; rz = hp[b*30+5]; }
        else        { rx = h45[(t-1)*3]; ry = h45[(t-1)*3+1]; rz = h45[(t-1)*3+2]; }
        float th = sqrtf(rx*rx + ry*ry + rz*rz + 1e-16f);
        float kx = rx/th, ky = ry/th, kz = rz/th;
        float cc = cosf(th), s = sinf(th), o = 1.0f - cc;
        sR[t*9+0] = cc + o*kx*kx;     sR[t*9+1] = -s*kz + o*kx*ky;  sR[t*9+2] =  s*ky + o*kx*kz;
        sR[t*9+3] =  s*kz + o*ky*kx;  sR[t*9+4] = cc + o*ky*ky;     sR[t*9+5] = -s*kx + o*ky*kz;
        sR[t*9+6] = -s*ky + o*kz*kx;  sR[t*9+7] =  s*kx + o*kz*ky;  sR[t*9+8] = cc + o*kz*kz;
    }
    if (t >= 64 && t < 64 + NJ*3) {
        int o = t - 64;
        float acc = C0[o];
        #pragma unroll
        for (int k = 0; k < NBETA; ++k) acc += C1[o*NBETA + k] * beta[b*NBETA + k];
        sJ[o] = acc;
    }
    __syncthreads();

    // phase 3: kinematic chain (thread m owns row m)
    if (t < 3) {
        const int par[NJ] = {-1,0,1,2,0,4,5,0,7,8,0,10,11,0,13,14};
        int m = t;
        float Tr[NJ][3], Tt[NJ];
        Tr[0][0] = sR[m*3+0]; Tr[0][1] = sR[m*3+1]; Tr[0][2] = sR[m*3+2];
        Tt[0] = sJ[m];
        #pragma unroll
        for (int j = 1; j < NJ; ++j) {
            int p = par[j];
            float t0 = sJ[j*3+0] - sJ[p*3+0];
            float t1 = sJ[j*3+1] - sJ[p*3+1];
            float t2 = sJ[j*3+2] - sJ[p*3+2];
            float a0 = Tr[p][0], a1 = Tr[p][1], a2 = Tr[p][2];
            #pragma unroll
            for (int n = 0; n < 3; ++n)
                Tr[j][n] = a0*sR[j*9+n] + a1*sR[j*9+3+n] + a2*sR[j*9+6+n];
            Tt[j] = a0*t0 + a1*t1 + a2*t2 + Tt[p];
        }
        #pragma unroll
        for (int j = 0; j < NJ; ++j) {
            float corr = Tr[j][0]*sJ[j*3] + Tr[j][1]*sJ[j*3+1] + Tr[j][2]*sJ[j*3+2];
            sA4[j*3 + m] = make_float4(Tr[j][0], Tr[j][1], Tr[j][2], Tt[j] - corr);
        }
    }
    __syncthreads();

    // phase 4: LBS
    float tx = hp[b*30+0], ty = hp[b*30+1], tz = hp[b*30+2];
    for (int v = t; v < NV; v += 256) {
        float4 r0 = make_float4(0,0,0,0), r1 = make_float4(0,0,0,0), r2 = make_float4(0,0,0,0);
        const float* w = W + v * NJ;
        for (int j = 0; j < NJ; ++j) {
            float wj = w[j];
            float4 A0 = sA4[j*3+0], A1 = sA4[j*3+1], A2 = sA4[j*3+2];
            r0.x += wj*A0.x; r0.y += wj*A0.y; r0.z += wj*A0.z; r0.w += wj*A0.w;
            r1.x += wj*A1.x; r1.y += wj*A1.y; r1.z += wj*A1.z; r1.w += wj*A1.w;
            r2.x += wj*A2.x; r2.y += wj*A2.y; r2.z += wj*A2.z; r2.w += wj*A2.w;
        }
        float px = VP[b*VD + v*3], py = VP[b*VD + v*3+1], pz = VP[b*VD + v*3+2];
        float x = r0.x*px + r0.y*py + r0.z*pz + r0.w + tx;
        float y = r1.x*px + r1.y*py + r1.z*pz + r1.w + ty;
        float z = r2.x*px + r2.y*py + r2.z*pz + r2.w + tz;
        sv[v*3] = x; sv[v*3+1] = y; sv[v*3+2] = z;
        int i = b*NV + v;
        verts[i*3] = x; verts[i*3+1] = y; verts[i*3+2] = z;
        PK[b*NVQ + v] = make_float4(x, y, z, 0.5f*(x*x + y*y + z*z));
    }
    __syncthreads();

    // phase 5: face normals into LDS accumulator
    for (int f = t; f < FC; f += 256) {
        int i0 = faces[f*3], i1 = faces[f*3+1], i2 = faces[f*3+2];
        float ax = sv[i1*3+0]-sv[i0*3+0], ay = sv[i1*3+1]-sv[i0*3+1], az = sv[i1*3+2]-sv[i0*3+2];
        float bx = sv[i2*3+0]-sv[i0*3+0], by = sv[i2*3+1]-sv[i0*3+1], bz = sv[i2*3+2]-sv[i0*3+2];
        float cx = ay*bz - az*by, cy = az*bx - ax*bz, cz = ax*by - ay*bx;
        atomicAdd(&sn[i0*3+0], cx); atomicAdd(&sn[i0*3+1], cy); atomicAdd(&sn[i0*3+2], cz);
        atomicAdd(&sn[i1*3+0], cx); atomicAdd(&sn[i1*3+1], cy); atomicAdd(&sn[i1*3+2], cz);
        atomicAdd(&sn[i2*3+0], cx); atomicAdd(&sn[i2*3+1], cy); atomicAdd(&sn[i2*3+2], cz);
    }
    __syncthreads();

    // phase 6: outputs
    for (int i = t; i < VD; i += 256) NRM[b*VD + i] = sn[i];
    if (t < NA*3) {
        int a = t / 3, d = t % 3;
        float acc = 0.0f;
        #pragma unroll
        for (int k = 0; k < 3; ++k)
            acc += aw[a*3 + k] * sv[afi[a*3 + k]*3 + d];
        contact[b*NA*3 + t] = acc;
    }
}

// one vertex vs both points; ascending vidx + strict < == jnp.argmin first-index
#define PROC1(vk, vidx) {                                                        \
    float d0 = fmaf(-ox0, (vk).x, (vk).w);                                       \
    d0 = fmaf(-oy0, (vk).y, d0); d0 = fmaf(-oz0, (vk).z, d0);                    \
    if (d0 < s0) { s0 = d0; j0 = (vidx); }                                       \
    float d1 = fmaf(-ox1, (vk).x, (vk).w);                                       \
    d1 = fmaf(-oy1, (vk).y, d1); d1 = fmaf(-oz1, (vk).z, d1);                    \
    if (d1 < s1) { s1 = d1; j1 = (vidx); } }

#define PROC8(buf, gbase) {                                                      \
    PROC1((buf)[0], (gbase)+0); PROC1((buf)[1], (gbase)+1);                      \
    PROC1((buf)[2], (gbase)+2); PROC1((buf)[3], (gbase)+3);                      \
    PROC1((buf)[4], (gbase)+4); PROC1((buf)[5], (gbase)+5);                      \
    PROC1((buf)[6], (gbase)+6); PROC1((buf)[7], (gbase)+7); }

// ---------------- Kernel 3: NN search (R7's ping-pong structure, standalone).
__global__ __launch_bounds__(256) void k_nn(const float* __restrict__ obj,
                                            const float4* __restrict__ PK,
                                            const float* __restrict__ NRM,
                                            float* __restrict__ cmap,
                                            float* __restrict__ pen)
{
    int blk = blockIdx.x;
    int b = blk >> 5;                 // batch
    int g = blk & 31;                 // point-group within batch
    int t = threadIdx.x, lane = t & 63, wid = t >> 6;

    __shared__ float4 sPK[NVQ];
    __shared__ float wsum[4];

    int n0 = g*512 + t;
    int n1 = n0 + 256;
    const float* o0p = obj + (b*NOBJ + n0)*3;
    const float* o1p = obj + (b*NOBJ + n1)*3;
    float ox0 = o0p[0], oy0 = o0p[1], oz0 = o0p[2];
    float ox1 = o1p[0], oy1 = o1p[1], oz1 = o1p[2];

    for (int i = t; i < NVQ; i += 256) sPK[i] = PK[b*NVQ + i];
    __syncthreads();

    float s0 = 1e30f, s1 = 1e30f;
    int j0 = 0, j1 = 0;
    {
        float4 A[8], B[8];
        #pragma unroll
        for (int k = 0; k < 8; ++k) A[k] = sPK[k];           // prologue: group 0
        for (int gg = 0; gg + 2 <= NG; gg += 2) {
            #pragma unroll
            for (int k = 0; k < 8; ++k) B[k] = sPK[(gg+1)*8 + k];  // issue g+1
            PROC8(A, gg*8);                                         // compute g
            if (gg + 2 < NG) {
                #pragma unroll
                for (int k = 0; k < 8; ++k) A[k] = sPK[(gg+2)*8 + k];  // issue g+2
            }
            PROC8(B, (gg+1)*8);                                     // compute g+1
        }
    }

    int base = b * NV;
    float osq0 = ox0*ox0 + oy0*oy0 + oz0*oz0;
    float d20 = 2.0f * s0 + osq0;
    cmap[b*NOBJ + n0] = 2.0f / (1.0f + __expf(100.0f * d20));
    float4 q0 = sPK[j0];
    float dp0 = (q0.x - ox0)*NRM[(base+j0)*3+0] + (q0.y - oy0)*NRM[(base+j0)*3+1]
              + (q0.z - oz0)*NRM[(base+j0)*3+2];
    float p = (dp0 > 0.0f) ? d20 : 0.0f;

    float osq1 = ox1*ox1 + oy1*oy1 + oz1*oz1;
    float d21 = 2.0f * s1 + osq1;
    cmap[b*NOBJ + n1] = 2.0f / (1.0f + __expf(100.0f * d21));
    float4 q1 = sPK[j1];
    float dp1 = (q1.x - ox1)*NRM[(base+j1)*3+0] + (q1.y - oy1)*NRM[(base+j1)*3+1]
              + (q1.z - oz1)*NRM[(base+j1)*3+2];
    p += (dp1 > 0.0f) ? d21 : 0.0f;

    for (int off = 32; off; off >>= 1) p += __shfl_down(p, off, 64);
    if (lane == 0) wsum[wid] = p;
    __syncthreads();
    if (t == 0) atomicAdd(pen, (wsum[0] + wsum[1] + wsum[2] + wsum[3]) * (1.0f / NB));
}

extern "C" void kernel_launch(void* const* d_in, const int* in_sizes, int n_in,
                              void* d_out, int out_size, void* d_ws, size_t ws_size,
                              hipStream_t stream)
{
    const float* hp    = (const float*)d_in[0];
    const float* obj   = (const float*)d_in[1];
    const float* beta  = (const float*)d_in[2];
    const float* vt    = (const float*)d_in[3];
    const float* sd    = (const float*)d_in[4];
    const float* pd    = (const float*)d_in[5];
    const float* Jreg  = (const float*)d_in[6];
    const float* W     = (const float*)d_in[7];
    const float* pca   = (const float*)d_in[8];
    const float* aw    = (const float*)d_in[9];
    const int*   faces = (const int*)d_in[10];
    const int*   afi   = (const int*)d_in[11];

    float* out     = (float*)d_out;
    float* cmap    = out;                          // 131072
    float* pen     = out + NB*NOBJ;                // 1
    float* verts   = out + NB*NOBJ + 1;            // 18672
    float* contact = out + NB*NOBJ + 1 + NB*NV*3;  // 768

    float* ws   = (float*)d_ws;
    float4* PK  = (float4*)ws;        // NB*NVQ float4
    float* NRM  = ws + NB*NVQ*4;      // NB*VD
    float* VP   = NRM + NB*VD;        // NB*VD
    float* C0   = VP + NB*VD;         // 48
    float* C1   = C0 + 48;            // 480

    k_blend<<<NB*BCH + NCB, 256, 0, stream>>>(hp, pca, vt, sd, pd, beta, Jreg,
                                              VP, C0, C1, pen);
    k_skel2<<<NB, 256, 0, stream>>>(hp, pca, beta, C0, C1, W, VP, faces, aw, afi,
                                    verts, PK, NRM, contact);
    k_nn   <<<NB*32, 256, 0, stream>>>(obj, PK, NRM, cmap, pen);
}

// Round 11
// 147.333 us; speedup vs baseline: 1.8093x; 1.8093x over previous
//
#include <hip/hip_runtime.h>
#include <math.h>

#define NV 778
#define NJ 16
#define NCOMP 24
#define NBETA 10
#define FC 1554
#define NA 32
#define NB 8
#define NOBJ 16384
#define VD (NV*3)          // 2334
#define BCH 584            // ceil(VD/4) row-chunks per batch for k_blend
#define NVQ 832            // padded vertex slots (104 groups of 8)
#define NG 104             // NVQ/8 groups
#define NCB 132            // extra C-blocks (528 outputs, one WAVE each)

// ---------------- Kernel 1: fused pose + blendshapes + C0/C1 side-compute.
// Main blocks (proven R1 structure): VP = vt + sd*beta + pd*posefeat.
// 132 extra blocks compute C0[48] = Jreg@vt and C1[480] = Jreg@sd with one
// WAVE per output (lane-parallel over v, butterfly reduce) — R9's serial
// per-thread loop was a 146us straggler; this is ~13 coalesced iterations.
__global__ __launch_bounds__(256) void k_blend(
    const float* __restrict__ hp, const float* __restrict__ pca,
    const float* __restrict__ vt, const float* __restrict__ sd,
    const float* __restrict__ pd, const float* __restrict__ beta,
    const float* __restrict__ Jreg,
    float* __restrict__ VP, float* __restrict__ C0, float* __restrict__ C1,
    float* __restrict__ pen)
{
    int bid = blockIdx.x;
    int t = threadIdx.x;
    int wid = t >> 6, lane = t & 63;

    if (bid >= NB*BCH) {               // ---- C-blocks: one wave per output
        int o = (bid - NB*BCH)*4 + wid;          // 0..527
        if (o < 528) {
            int jd, k;
            if (o < 48) { jd = o; k = -1; }
            else        { jd = (o-48)/NBETA; k = (o-48)%NBETA; }
            int j = jd/3, d = jd%3;
            const float* jr = Jreg + j*NV;
            float acc = 0.0f;
            for (int v = lane; v < NV; v += 64) {
                float x = (k < 0) ? vt[v*3+d] : sd[(v*3+d)*NBETA + k];
                acc += jr[v] * x;
            }
            #pragma unroll
            for (int off = 32; off; off >>= 1) acc += __shfl_down(acc, off, 64);
            if (lane == 0) { if (k < 0) C0[jd] = acc; else C1[jd*NBETA + k] = acc; }
        }
        return;
    }

    int b = bid / BCH, c = bid % BCH;
    __shared__ float h45[45];
    __shared__ float sR[NJ*9];
    __shared__ float spf[135];

    if (t < 45) {
        float acc = 0.0f;
        #pragma unroll
        for (int k = 0; k < NCOMP; ++k) acc += hp[b*30 + 6 + k] * pca[k*45 + t];
        h45[t] = acc;
    }
    __syncthreads();
    if (t < NJ) {
        float rx, ry, rz;
        if (t == 0) { rx = hp[b*30+3]; ry = hp[b*30+4]; rz = hp[b*30+5]; }
        else        { rx = h45[(t-1)*3]; ry = h45[(t-1)*3+1]; rz = h45[(t-1)*3+2]; }
        float th = sqrtf(rx*rx + ry*ry + rz*rz + 1e-16f);
        float kx = rx/th, ky = ry/th, kz = rz/th;
        float cc = cosf(th), s = sinf(th), o = 1.0f - cc;
        float R[9];
        R[0] = cc + o*kx*kx;     R[1] = -s*kz + o*kx*ky;  R[2] =  s*ky + o*kx*kz;
        R[3] =  s*kz + o*ky*kx;  R[4] = cc + o*ky*ky;     R[5] = -s*kx + o*ky*kz;
        R[6] = -s*ky + o*kz*kx;  R[7] =  s*kx + o*kz*ky;  R[8] = cc + o*kz*kz;
        #pragma unroll
        for (int i = 0; i < 9; ++i) sR[t*9+i] = R[i];
    }
    __syncthreads();
    if (t < 135) {
        int mn = t % 9;
        float d = (mn == 0 || mn == 4 || mn == 8) ? 1.0f : 0.0f;
        spf[t] = sR[9 + t] - d;
    }
    if (bid == 0 && t == 0) *pen = 0.0f;
    __syncthreads();

    int r = c*4 + wid;                 // row within batch: v*3 + d
    if (r < VD) {
        const float* p  = pd + r * 135;
        float accP = p[lane] * spf[lane] + p[lane+64] * spf[lane+64];
        accP += (lane < 7) ? p[lane+128] * spf[lane+128] : 0.0f;

        float accS = (lane < NBETA) ? sd[r*NBETA + lane] * beta[b*NBETA + lane] : 0.0f;

        #pragma unroll
        for (int off = 32; off; off >>= 1) {
            accP += __shfl_down(accP, off, 64);
            accS += __shfl_down(accS, off, 64);
        }
        if (lane == 0) VP[b*VD + r] = vt[r] + accS + accP;
    }
}

// ---------------- Kernel 2: skel-lite — J from C0/C1, chain, LBS, normals.
// No Jreg/VS reads (the 13-iteration global reduce is gone). 8 blocks x 256.
__global__ __launch_bounds__(256) void k_skel2(
    const float* __restrict__ hp, const float* __restrict__ pca,
    const float* __restrict__ beta,
    const float* __restrict__ C0, const float* __restrict__ C1,
    const float* __restrict__ W, const float* __restrict__ VP,
    const int* __restrict__ faces, const float* __restrict__ aw,
    const int* __restrict__ afi,
    float* __restrict__ verts, float4* __restrict__ PK,
    float* __restrict__ NRM, float* __restrict__ contact)
{
    int b = blockIdx.x, t = threadIdx.x;
    __shared__ float h45[45];
    __shared__ float sR[NJ*9];
    __shared__ float sJ[NJ*3];
    __shared__ float4 sA4[NJ*3];
    __shared__ float sv[VD];
    __shared__ float sn[VD];

    // phase 1: PCA matvec + LDS init + PK sentinels
    if (t < 45) {
        float acc = 0.0f;
        #pragma unroll
        for (int k = 0; k < NCOMP; ++k) acc += hp[b*30 + 6 + k] * pca[k*45 + t];
        h45[t] = acc;
    }
    for (int i = t; i < VD; i += 256) sn[i] = 0.0f;
    if (t < NVQ - NV) PK[b*NVQ + NV + t] = make_float4(0.f, 0.f, 0.f, 1e30f);
    __syncthreads();

    // phase 2: Rodrigues (wave 0) + joints from C0/C1 (wave 1)
    if (t < NJ) {
        float rx, ry, rz;
        if (t == 0) { rx = hp[b*30+3]; ry = hp[b*30+4]; rz = hp[b*30+5]; }
        else        { rx = h45[(t-1)*3]; ry = h45[(t-1)*3+1]; rz = h45[(t-1)*3+2]; }
        float th = sqrtf(rx*rx + ry*ry + rz*rz + 1e-16f);
        float kx = rx/th, ky = ry/th, kz = rz/th;
        float cc = cosf(th), s = sinf(th), o = 1.0f - cc;
        sR[t*9+0] = cc + o*kx*kx;     sR[t*9+1] = -s*kz + o*kx*ky;  sR[t*9+2] =  s*ky + o*kx*kz;
        sR[t*9+3] =  s*kz + o*ky*kx;  sR[t*9+4] = cc + o*ky*ky;     sR[t*9+5] = -s*kx + o*ky*kz;
        sR[t*9+6] = -s*ky + o*kz*kx;  sR[t*9+7] =  s*kx + o*kz*ky;  sR[t*9+8] = cc + o*kz*kz;
    }
    if (t >= 64 && t < 64 + NJ*3) {
        int o = t - 64;
        float acc = C0[o];
        #pragma unroll
        for (int k = 0; k < NBETA; ++k) acc += C1[o*NBETA + k] * beta[b*NBETA + k];
        sJ[o] = acc;
    }
    __syncthreads();

    // phase 3: kinematic chain (thread m owns row m)
    if (t < 3) {
        const int par[NJ] = {-1,0,1,2,0,4,5,0,7,8,0,10,11,0,13,14};
        int m = t;
        float Tr[NJ][3], Tt[NJ];
        Tr[0][0] = sR[m*3+0]; Tr[0][1] = sR[m*3+1]; Tr[0][2] = sR[m*3+2];
        Tt[0] = sJ[m];
        #pragma unroll
        for (int j = 1; j < NJ; ++j) {
            int p = par[j];
            float t0 = sJ[j*3+0] - sJ[p*3+0];
            float t1 = sJ[j*3+1] - sJ[p*3+1];
            float t2 = sJ[j*3+2] - sJ[p*3+2];
            float a0 = Tr[p][0], a1 = Tr[p][1], a2 = Tr[p][2];
            #pragma unroll
            for (int n = 0; n < 3; ++n)
                Tr[j][n] = a0*sR[j*9+n] + a1*sR[j*9+3+n] + a2*sR[j*9+6+n];
            Tt[j] = a0*t0 + a1*t1 + a2*t2 + Tt[p];
        }
        #pragma unroll
        for (int j = 0; j < NJ; ++j) {
            float corr = Tr[j][0]*sJ[j*3] + Tr[j][1]*sJ[j*3+1] + Tr[j][2]*sJ[j*3+2];
            sA4[j*3 + m] = make_float4(Tr[j][0], Tr[j][1], Tr[j][2], Tt[j] - corr);
        }
    }
    __syncthreads();

    // phase 4: LBS
    float tx = hp[b*30+0], ty = hp[b*30+1], tz = hp[b*30+2];
    for (int v = t; v < NV; v += 256) {
        float4 r0 = make_float4(0,0,0,0), r1 = make_float4(0,0,0,0), r2 = make_float4(0,0,0,0);
        const float* w = W + v * NJ;
        for (int j = 0; j < NJ; ++j) {
            float wj = w[j];
            float4 A0 = sA4[j*3+0], A1 = sA4[j*3+1], A2 = sA4[j*3+2];
            r0.x += wj*A0.x; r0.y += wj*A0.y; r0.z += wj*A0.z; r0.w += wj*A0.w;
            r1.x += wj*A1.x; r1.y += wj*A1.y; r1.z += wj*A1.z; r1.w += wj*A1.w;
            r2.x += wj*A2.x; r2.y += wj*A2.y; r2.z += wj*A2.z; r2.w += wj*A2.w;
        }
        float px = VP[b*VD + v*3], py = VP[b*VD + v*3+1], pz = VP[b*VD + v*3+2];
        float x = r0.x*px + r0.y*py + r0.z*pz + r0.w + tx;
        float y = r1.x*px + r1.y*py + r1.z*pz + r1.w + ty;
        float z = r2.x*px + r2.y*py + r2.z*pz + r2.w + tz;
        sv[v*3] = x; sv[v*3+1] = y; sv[v*3+2] = z;
        int i = b*NV + v;
        verts[i*3] = x; verts[i*3+1] = y; verts[i*3+2] = z;
        PK[b*NVQ + v] = make_float4(x, y, z, 0.5f*(x*x + y*y + z*z));
    }
    __syncthreads();

    // phase 5: face normals into LDS accumulator
    for (int f = t; f < FC; f += 256) {
        int i0 = faces[f*3], i1 = faces[f*3+1], i2 = faces[f*3+2];
        float ax = sv[i1*3+0]-sv[i0*3+0], ay = sv[i1*3+1]-sv[i0*3+1], az = sv[i1*3+2]-sv[i0*3+2];
        float bx = sv[i2*3+0]-sv[i0*3+0], by = sv[i2*3+1]-sv[i0*3+1], bz = sv[i2*3+2]-sv[i0*3+2];
        float cx = ay*bz - az*by, cy = az*bx - ax*bz, cz = ax*by - ay*bx;
        atomicAdd(&sn[i0*3+0], cx); atomicAdd(&sn[i0*3+1], cy); atomicAdd(&sn[i0*3+2], cz);
        atomicAdd(&sn[i1*3+0], cx); atomicAdd(&sn[i1*3+1], cy); atomicAdd(&sn[i1*3+2], cz);
        atomicAdd(&sn[i2*3+0], cx); atomicAdd(&sn[i2*3+1], cy); atomicAdd(&sn[i2*3+2], cz);
    }
    __syncthreads();

    // phase 6: outputs
    for (int i = t; i < VD; i += 256) NRM[b*VD + i] = sn[i];
    if (t < NA*3) {
        int a = t / 3, d = t % 3;
        float acc = 0.0f;
        #pragma unroll
        for (int k = 0; k < 3; ++k)
            acc += aw[a*3 + k] * sv[afi[a*3 + k]*3 + d];
        contact[b*NA*3 + t] = acc;
    }
}

// one vertex vs both points; ascending vidx + strict < == jnp.argmin first-index
#define PROC1(vk, vidx) {                                                        \
    float d0 = fmaf(-ox0, (vk).x, (vk).w);                                       \
    d0 = fmaf(-oy0, (vk).y, d0); d0 = fmaf(-oz0, (vk).z, d0);                    \
    if (d0 < s0) { s0 = d0; j0 = (vidx); }                                       \
    float d1 = fmaf(-ox1, (vk).x, (vk).w);                                       \
    d1 = fmaf(-oy1, (vk).y, d1); d1 = fmaf(-oz1, (vk).z, d1);                    \
    if (d1 < s1) { s1 = d1; j1 = (vidx); } }

#define PROC8(buf, gbase) {                                                      \
    PROC1((buf)[0], (gbase)+0); PROC1((buf)[1], (gbase)+1);                      \
    PROC1((buf)[2], (gbase)+2); PROC1((buf)[3], (gbase)+3);                      \
    PROC1((buf)[4], (gbase)+4); PROC1((buf)[5], (gbase)+5);                      \
    PROC1((buf)[6], (gbase)+6); PROC1((buf)[7], (gbase)+7); }

// ---------------- Kernel 3: NN search (R7's ping-pong structure, standalone).
__global__ __launch_bounds__(256) void k_nn(const float* __restrict__ obj,
                                            const float4* __restrict__ PK,
                                            const float* __restrict__ NRM,
                                            float* __restrict__ cmap,
                                            float* __restrict__ pen)
{
    int blk = blockIdx.x;
    int b = blk >> 5;                 // batch
    int g = blk & 31;                 // point-group within batch
    int t = threadIdx.x, lane = t & 63, wid = t >> 6;

    __shared__ float4 sPK[NVQ];
    __shared__ float wsum[4];

    int n0 = g*512 + t;
    int n1 = n0 + 256;
    const float* o0p = obj + (b*NOBJ + n0)*3;
    const float* o1p = obj + (b*NOBJ + n1)*3;
    float ox0 = o0p[0], oy0 = o0p[1], oz0 = o0p[2];
    float ox1 = o1p[0], oy1 = o1p[1], oz1 = o1p[2];

    for (int i = t; i < NVQ; i += 256) sPK[i] = PK[b*NVQ + i];
    __syncthreads();

    float s0 = 1e30f, s1 = 1e30f;
    int j0 = 0, j1 = 0;
    {
        float4 A[8], B[8];
        #pragma unroll
        for (int k = 0; k < 8; ++k) A[k] = sPK[k];           // prologue: group 0
        for (int gg = 0; gg + 2 <= NG; gg += 2) {
            #pragma unroll
            for (int k = 0; k < 8; ++k) B[k] = sPK[(gg+1)*8 + k];  // issue g+1
            PROC8(A, gg*8);                                         // compute g
            if (gg + 2 < NG) {
                #pragma unroll
                for (int k = 0; k < 8; ++k) A[k] = sPK[(gg+2)*8 + k];  // issue g+2
            }
            PROC8(B, (gg+1)*8);                                     // compute g+1
        }
    }

    int base = b * NV;
    float osq0 = ox0*ox0 + oy0*oy0 + oz0*oz0;
    float d20 = 2.0f * s0 + osq0;
    cmap[b*NOBJ + n0] = 2.0f / (1.0f + __expf(100.0f * d20));
    float4 q0 = sPK[j0];
    float dp0 = (q0.x - ox0)*NRM[(base+j0)*3+0] + (q0.y - oy0)*NRM[(base+j0)*3+1]
              + (q0.z - oz0)*NRM[(base+j0)*3+2];
    float p = (dp0 > 0.0f) ? d20 : 0.0f;

    float osq1 = ox1*ox1 + oy1*oy1 + oz1*oz1;
    float d21 = 2.0f * s1 + osq1;
    cmap[b*NOBJ + n1] = 2.0f / (1.0f + __expf(100.0f * d21));
    float4 q1 = sPK[j1];
    float dp1 = (q1.x - ox1)*NRM[(base+j1)*3+0] + (q1.y - oy1)*NRM[(base+j1)*3+1]
              + (q1.z - oz1)*NRM[(base+j1)*3+2];
    p += (dp1 > 0.0f) ? d21 : 0.0f;

    for (int off = 32; off; off >>= 1) p += __shfl_down(p, off, 64);
    if (lane == 0) wsum[wid] = p;
    __syncthreads();
    if (t == 0) atomicAdd(pen, (wsum[0] + wsum[1] + wsum[2] + wsum[3]) * (1.0f / NB));
}

extern "C" void kernel_launch(void* const* d_in, const int* in_sizes, int n_in,
                              void* d_out, int out_size, void* d_ws, size_t ws_size,
                              hipStream_t stream)
{
    const float* hp    = (const float*)d_in[0];
    const float* obj   = (const float*)d_in[1];
    const float* beta  = (const float*)d_in[2];
    const float* vt    = (const float*)d_in[3];
    const float* sd    = (const float*)d_in[4];
    const float* pd    = (const float*)d_in[5];
    const float* Jreg  = (const float*)d_in[6];
    const float* W     = (const float*)d_in[7];
    const float* pca   = (const float*)d_in[8];
    const float* aw    = (const float*)d_in[9];
    const int*   faces = (const int*)d_in[10];
    const int*   afi   = (const int*)d_in[11];

    float* out     = (float*)d_out;
    float* cmap    = out;                          // 131072
    float* pen     = out + NB*NOBJ;                // 1
    float* verts   = out + NB*NOBJ + 1;            // 18672
    float* contact = out + NB*NOBJ + 1 + NB*NV*3;  // 768

    float* ws   = (float*)d_ws;
    float4* PK  = (float4*)ws;        // NB*NVQ float4
    float* NRM  = ws + NB*NVQ*4;      // NB*VD
    float* VP   = NRM + NB*VD;        // NB*VD
    float* C0   = VP + NB*VD;         // 48
    float* C1   = C0 + 48;            // 480

    k_blend<<<NB*BCH + NCB, 256, 0, stream>>>(hp, pca, vt, sd, pd, beta, Jreg,
                                              VP, C0, C1, pen);
    k_skel2<<<NB, 256, 0, stream>>>(hp, pca, beta, C0, C1, W, VP, faces, aw, afi,
                                    verts, PK, NRM, contact);
    k_nn   <<<NB*32, 256, 0, stream>>>(obj, PK, NRM, cmap, pen);
}

// Round 12
// 141.699 us; speedup vs baseline: 1.8812x; 1.0398x over previous
//
#include <hip/hip_runtime.h>
#include <math.h>

#define NV 778
#define NJ 16
#define NCOMP 24
#define NBETA 10
#define FC 1554
#define NA 32
#define NB 8
#define NOBJ 16384
#define VD (NV*3)          // 2334
#define BCH 584            // ceil(VD/4) row-chunks per batch for k_blend
#define NVQ 832            // padded vertex slots (104 groups of 8)
#define NG 104             // NVQ/8 groups
#define NCB 132            // extra C-blocks (528 outputs, one WAVE each)

// ---------------- Kernel 1: fused pose + blendshapes + C0/C1 side-compute.
// Main blocks: VP = vt + sd*beta + pd*posefeat. 132 extra blocks compute
// C0[48] = Jreg@vt and C1[480] = Jreg@sd, one WAVE per output (R10 fix).
__global__ __launch_bounds__(256) void k_blend(
    const float* __restrict__ hp, const float* __restrict__ pca,
    const float* __restrict__ vt, const float* __restrict__ sd,
    const float* __restrict__ pd, const float* __restrict__ beta,
    const float* __restrict__ Jreg,
    float* __restrict__ VP, float* __restrict__ C0, float* __restrict__ C1,
    float* __restrict__ pen)
{
    int bid = blockIdx.x;
    int t = threadIdx.x;
    int wid = t >> 6, lane = t & 63;

    if (bid >= NB*BCH) {               // ---- C-blocks: one wave per output
        int o = (bid - NB*BCH)*4 + wid;          // 0..527
        if (o < 528) {
            int jd, k;
            if (o < 48) { jd = o; k = -1; }
            else        { jd = (o-48)/NBETA; k = (o-48)%NBETA; }
            int j = jd/3, d = jd%3;
            const float* jr = Jreg + j*NV;
            float acc = 0.0f;
            for (int v = lane; v < NV; v += 64) {
                float x = (k < 0) ? vt[v*3+d] : sd[(v*3+d)*NBETA + k];
                acc += jr[v] * x;
            }
            #pragma unroll
            for (int off = 32; off; off >>= 1) acc += __shfl_down(acc, off, 64);
            if (lane == 0) { if (k < 0) C0[jd] = acc; else C1[jd*NBETA + k] = acc; }
        }
        return;
    }

    int b = bid / BCH, c = bid % BCH;
    __shared__ float h45[45];
    __shared__ float sR[NJ*9];
    __shared__ float spf[135];

    if (t < 45) {
        float acc = 0.0f;
        #pragma unroll
        for (int k = 0; k < NCOMP; ++k) acc += hp[b*30 + 6 + k] * pca[k*45 + t];
        h45[t] = acc;
    }
    __syncthreads();
    if (t < NJ) {
        float rx, ry, rz;
        if (t == 0) { rx = hp[b*30+3]; ry = hp[b*30+4]; rz = hp[b*30+5]; }
        else        { rx = h45[(t-1)*3]; ry = h45[(t-1)*3+1]; rz = h45[(t-1)*3+2]; }
        float th = sqrtf(rx*rx + ry*ry + rz*rz + 1e-16f);
        float kx = rx/th, ky = ry/th, kz = rz/th;
        float cc = cosf(th), s = sinf(th), o = 1.0f - cc;
        float R[9];
        R[0] = cc + o*kx*kx;     R[1] = -s*kz + o*kx*ky;  R[2] =  s*ky + o*kx*kz;
        R[3] =  s*kz + o*ky*kx;  R[4] = cc + o*ky*ky;     R[5] = -s*kx + o*ky*kz;
        R[6] = -s*ky + o*kz*kx;  R[7] =  s*kx + o*kz*ky;  R[8] = cc + o*kz*kz;
        #pragma unroll
        for (int i = 0; i < 9; ++i) sR[t*9+i] = R[i];
    }
    __syncthreads();
    if (t < 135) {
        int mn = t % 9;
        float d = (mn == 0 || mn == 4 || mn == 8) ? 1.0f : 0.0f;
        spf[t] = sR[9 + t] - d;
    }
    if (bid == 0 && t == 0) *pen = 0.0f;
    __syncthreads();

    int r = c*4 + wid;                 // row within batch: v*3 + d
    if (r < VD) {
        const float* p  = pd + r * 135;
        float accP = p[lane] * spf[lane] + p[lane+64] * spf[lane+64];
        accP += (lane < 7) ? p[lane+128] * spf[lane+128] : 0.0f;

        float accS = (lane < NBETA) ? sd[r*NBETA + lane] * beta[b*NBETA + lane] : 0.0f;

        #pragma unroll
        for (int off = 32; off; off >>= 1) {
            accP += __shfl_down(accP, off, 64);
            accS += __shfl_down(accS, off, 64);
        }
        if (lane == 0) VP[b*VD + r] = vt[r] + accS + accP;
    }
}

// one vertex vs both points; ascending vidx + strict < == jnp.argmin first-index
#define PROC1(vk, vidx) {                                                        \
    float d0 = fmaf(-ox0, (vk).x, (vk).w);                                       \
    d0 = fmaf(-oy0, (vk).y, d0); d0 = fmaf(-oz0, (vk).z, d0);                    \
    if (d0 < s0) { s0 = d0; j0 = (vidx); }                                       \
    float d1 = fmaf(-ox1, (vk).x, (vk).w);                                       \
    d1 = fmaf(-oy1, (vk).y, d1); d1 = fmaf(-oz1, (vk).z, d1);                    \
    if (d1 < s1) { s1 = d1; j1 = (vidx); } }

#define PROC8(buf, gbase) {                                                      \
    PROC1((buf)[0], (gbase)+0); PROC1((buf)[1], (gbase)+1);                      \
    PROC1((buf)[2], (gbase)+2); PROC1((buf)[3], (gbase)+3);                      \
    PROC1((buf)[4], (gbase)+4); PROC1((buf)[5], (gbase)+5);                      \
    PROC1((buf)[6], (gbase)+6); PROC1((buf)[7], (gbase)+7); }

// ---------------- Kernel 2: MEGA2 — cheap skel prelude (C0/C1 joints) + NN.
// 256 blocks (32/batch). vs R5's mega: the 32x-replicated Jreg/VS joint
// reduction (the cold-memory monster, 40.8us standalone in R11) is replaced
// by 48 FMAs from C0/C1. Remaining per-block cold reads (W 50KB, VP, faces)
// overlap across 256 concurrent blocks instead of stalling 8.
__global__ __launch_bounds__(256) void k_mega2(
    const float* __restrict__ hp, const float* __restrict__ pca,
    const float* __restrict__ beta,
    const float* __restrict__ C0, const float* __restrict__ C1,
    const float* __restrict__ W, const float* __restrict__ VP,
    const int* __restrict__ faces, const float* __restrict__ aw,
    const int* __restrict__ afi, const float* __restrict__ obj,
    float* __restrict__ verts, float* __restrict__ cmap,
    float* __restrict__ contact, float* __restrict__ pen)
{
    int blk = blockIdx.x;
    int b = blk >> 5;                 // batch
    int g = blk & 31;                 // point-group within batch
    int t = threadIdx.x, lane = t & 63, wid = t >> 6;

    __shared__ float4 sPK[NVQ];       // {x,y,z,0.5*|v|^2}; 778..831 sentinels
    __shared__ float sv[VD];
    __shared__ float sn[VD];
    __shared__ float sR[NJ*9];
    __shared__ float sJ[NJ*3];
    __shared__ float4 sA4[NJ*3];
    __shared__ float h45[45];
    __shared__ float wsum[4];

    // object points: load first, hide HBM latency behind the prelude
    int n0 = g*512 + t;
    int n1 = n0 + 256;
    const float* o0p = obj + (b*NOBJ + n0)*3;
    const float* o1p = obj + (b*NOBJ + n1)*3;
    float ox0 = o0p[0], oy0 = o0p[1], oz0 = o0p[2];
    float ox1 = o1p[0], oy1 = o1p[1], oz1 = o1p[2];

    // ---- phase 1: PCA matvec + LDS init + sentinels
    if (t < 45) {
        float acc = 0.0f;
        #pragma unroll
        for (int k = 0; k < NCOMP; ++k) acc += hp[b*30 + 6 + k] * pca[k*45 + t];
        h45[t] = acc;
    }
    for (int i = t; i < VD; i += 256) sn[i] = 0.0f;
    if (t < NVQ - NV) sPK[NV + t] = make_float4(0.f, 0.f, 0.f, 1e30f);
    __syncthreads();

    // ---- phase 2: Rodrigues (wave 0) + joints from C0/C1 (wave 1)
    if (t < NJ) {
        float rx, ry, rz;
        if (t == 0) { rx = hp[b*30+3]; ry = hp[b*30+4]; rz = hp[b*30+5]; }
        else        { rx = h45[(t-1)*3]; ry = h45[(t-1)*3+1]; rz = h45[(t-1)*3+2]; }
        float th = sqrtf(rx*rx + ry*ry + rz*rz + 1e-16f);
        float kx = rx/th, ky = ry/th, kz = rz/th;
        float cc = cosf(th), s = sinf(th), o = 1.0f - cc;
        sR[t*9+0] = cc + o*kx*kx;     sR[t*9+1] = -s*kz + o*kx*ky;  sR[t*9+2] =  s*ky + o*kx*kz;
        sR[t*9+3] =  s*kz + o*ky*kx;  sR[t*9+4] = cc + o*ky*ky;     sR[t*9+5] = -s*kx + o*ky*kz;
        sR[t*9+6] = -s*ky + o*kz*kx;  sR[t*9+7] =  s*kx + o*kz*ky;  sR[t*9+8] = cc + o*kz*kz;
    }
    if (t >= 64 && t < 64 + NJ*3) {
        int o = t - 64;
        float acc = C0[o];
        #pragma unroll
        for (int k = 0; k < NBETA; ++k) acc += C1[o*NBETA + k] * beta[b*NBETA + k];
        sJ[o] = acc;
    }
    __syncthreads();

    // ---- phase 3: kinematic chain (thread m owns row m)
    if (t < 3) {
        const int par[NJ] = {-1,0,1,2,0,4,5,0,7,8,0,10,11,0,13,14};
        int m = t;
        float Tr[NJ][3], Tt[NJ];
        Tr[0][0] = sR[m*3+0]; Tr[0][1] = sR[m*3+1]; Tr[0][2] = sR[m*3+2];
        Tt[0] = sJ[m];
        #pragma unroll
        for (int j = 1; j < NJ; ++j) {
            int p = par[j];
            float t0 = sJ[j*3+0] - sJ[p*3+0];
            float t1 = sJ[j*3+1] - sJ[p*3+1];
            float t2 = sJ[j*3+2] - sJ[p*3+2];
            float a0 = Tr[p][0], a1 = Tr[p][1], a2 = Tr[p][2];
            #pragma unroll
            for (int n = 0; n < 3; ++n)
                Tr[j][n] = a0*sR[j*9+n] + a1*sR[j*9+3+n] + a2*sR[j*9+6+n];
            Tt[j] = a0*t0 + a1*t1 + a2*t2 + Tt[p];
        }
        #pragma unroll
        for (int j = 0; j < NJ; ++j) {
            float corr = Tr[j][0]*sJ[j*3] + Tr[j][1]*sJ[j*3+1] + Tr[j][2]*sJ[j*3+2];
            sA4[j*3 + m] = make_float4(Tr[j][0], Tr[j][1], Tr[j][2], Tt[j] - corr);
        }
    }
    __syncthreads();

    // ---- phase 4: LBS into sv + sPK (W rows as 4x float4)
    float tx = hp[b*30+0], ty = hp[b*30+1], tz = hp[b*30+2];
    for (int v = t; v < NV; v += 256) {
        float4 r0 = make_float4(0,0,0,0), r1 = make_float4(0,0,0,0), r2 = make_float4(0,0,0,0);
        const float4* w4 = (const float4*)(W + v * NJ);
        #pragma unroll
        for (int q = 0; q < 4; ++q) {
            float4 wv = w4[q];
            #pragma unroll
            for (int jj = 0; jj < 4; ++jj) {
                int j = q*4 + jj;
                float wj = (jj==0)?wv.x:(jj==1)?wv.y:(jj==2)?wv.z:wv.w;
                float4 A0 = sA4[j*3+0], A1 = sA4[j*3+1], A2 = sA4[j*3+2];
                r0.x += wj*A0.x; r0.y += wj*A0.y; r0.z += wj*A0.z; r0.w += wj*A0.w;
                r1.x += wj*A1.x; r1.y += wj*A1.y; r1.z += wj*A1.z; r1.w += wj*A1.w;
                r2.x += wj*A2.x; r2.y += wj*A2.y; r2.z += wj*A2.z; r2.w += wj*A2.w;
            }
        }
        float px = VP[b*VD + v*3], py = VP[b*VD + v*3+1], pz = VP[b*VD + v*3+2];
        float x = r0.x*px + r0.y*py + r0.z*pz + r0.w + tx;
        float y = r1.x*px + r1.y*py + r1.z*pz + r1.w + ty;
        float z = r2.x*px + r2.y*py + r2.z*pz + r2.w + tz;
        sv[v*3] = x; sv[v*3+1] = y; sv[v*3+2] = z;
        sPK[v] = make_float4(x, y, z, 0.5f*(x*x + y*y + z*z));
        if (g == 0) {
            int i = b*NV + v;
            verts[i*3] = x; verts[i*3+1] = y; verts[i*3+2] = z;
        }
    }
    __syncthreads();

    // ---- phase 5: face normals into LDS accumulator
    for (int f = t; f < FC; f += 256) {
        int i0 = faces[f*3], i1 = faces[f*3+1], i2 = faces[f*3+2];
        float ax = sv[i1*3+0]-sv[i0*3+0], ay = sv[i1*3+1]-sv[i0*3+1], az = sv[i1*3+2]-sv[i0*3+2];
        float bx = sv[i2*3+0]-sv[i0*3+0], by = sv[i2*3+1]-sv[i0*3+1], bz = sv[i2*3+2]-sv[i0*3+2];
        float cx = ay*bz - az*by, cy = az*bx - ax*bz, cz = ax*by - ay*bx;
        atomicAdd(&sn[i0*3+0], cx); atomicAdd(&sn[i0*3+1], cy); atomicAdd(&sn[i0*3+2], cz);
        atomicAdd(&sn[i1*3+0], cx); atomicAdd(&sn[i1*3+1], cy); atomicAdd(&sn[i1*3+2], cz);
        atomicAdd(&sn[i2*3+0], cx); atomicAdd(&sn[i2*3+1], cy); atomicAdd(&sn[i2*3+2], cz);
    }
    __syncthreads();

    // ---- contact candidates (one block per batch)
    if (g == 0 && t < NA*3) {
        int a = t / 3, d = t % 3;
        float acc = 0.0f;
        #pragma unroll
        for (int k = 0; k < 3; ++k)
            acc += aw[a*3 + k] * sv[afi[a*3 + k]*3 + d];
        contact[b*NA*3 + t] = acc;
    }

    // ---- NN scan: 104 groups of 8, ping-pong register staging (R7-proven)
    float s0 = 1e30f, s1 = 1e30f;
    int j0 = 0, j1 = 0;
    {
        float4 A[8], B[8];
        #pragma unroll
        for (int k = 0; k < 8; ++k) A[k] = sPK[k];           // prologue: group 0
        for (int gg = 0; gg + 2 <= NG; gg += 2) {
            #pragma unroll
            for (int k = 0; k < 8; ++k) B[k] = sPK[(gg+1)*8 + k];  // issue g+1
            PROC8(A, gg*8);                                         // compute g
            if (gg + 2 < NG) {
                #pragma unroll
                for (int k = 0; k < 8; ++k) A[k] = sPK[(gg+2)*8 + k];  // issue g+2
            }
            PROC8(B, (gg+1)*8);                                     // compute g+1
        }
    }

    // ---- epilogues (normals + nn-vert from LDS)
    float osq0 = ox0*ox0 + oy0*oy0 + oz0*oz0;
    float d20 = 2.0f * s0 + osq0;
    cmap[b*NOBJ + n0] = 2.0f / (1.0f + __expf(100.0f * d20));
    float4 q0 = sPK[j0];
    float dp0 = (q0.x - ox0)*sn[j0*3+0] + (q0.y - oy0)*sn[j0*3+1] + (q0.z - oz0)*sn[j0*3+2];
    float p = (dp0 > 0.0f) ? d20 : 0.0f;

    float osq1 = ox1*ox1 + oy1*oy1 + oz1*oz1;
    float d21 = 2.0f * s1 + osq1;
    cmap[b*NOBJ + n1] = 2.0f / (1.0f + __expf(100.0f * d21));
    float4 q1 = sPK[j1];
    float dp1 = (q1.x - ox1)*sn[j1*3+0] + (q1.y - oy1)*sn[j1*3+1] + (q1.z - oz1)*sn[j1*3+2];
    p += (dp1 > 0.0f) ? d21 : 0.0f;

    for (int off = 32; off; off >>= 1) p += __shfl_down(p, off, 64);
    if (lane == 0) wsum[wid] = p;
    __syncthreads();
    if (t == 0) atomicAdd(pen, (wsum[0] + wsum[1] + wsum[2] + wsum[3]) * (1.0f / NB));
}

extern "C" void kernel_launch(void* const* d_in, const int* in_sizes, int n_in,
                              void* d_out, int out_size, void* d_ws, size_t ws_size,
                              hipStream_t stream)
{
    const float* hp    = (const float*)d_in[0];
    const float* obj   = (const float*)d_in[1];
    const float* beta  = (const float*)d_in[2];
    const float* vt    = (const float*)d_in[3];
    const float* sd    = (const float*)d_in[4];
    const float* pd    = (const float*)d_in[5];
    const float* Jreg  = (const float*)d_in[6];
    const float* W     = (const float*)d_in[7];
    const float* pca   = (const float*)d_in[8];
    const float* aw    = (const float*)d_in[9];
    const int*   faces = (const int*)d_in[10];
    const int*   afi   = (const int*)d_in[11];

    float* out     = (float*)d_out;
    float* cmap    = out;                          // 131072
    float* pen     = out + NB*NOBJ;                // 1
    float* verts   = out + NB*NOBJ + 1;            // 18672
    float* contact = out + NB*NOBJ + 1 + NB*NV*3;  // 768

    float* ws   = (float*)d_ws;
    float* VP   = ws;                 // NB*VD
    float* C0   = VP + NB*VD;         // 48
    float* C1   = C0 + 48;            // 480

    k_blend<<<NB*BCH + NCB, 256, 0, stream>>>(hp, pca, vt, sd, pd, beta, Jreg,
                                              VP, C0, C1, pen);
    k_mega2<<<NB*32, 256, 0, stream>>>(hp, pca, beta, C0, C1, W, VP, faces, aw,
                                       afi, obj, verts, cmap, contact, pen);
}

// Round 13
// 133.732 us; speedup vs baseline: 1.9933x; 1.0596x over previous
//
#include <hip/hip_runtime.h>
#include <math.h>

#define NV 778
#define NJ 16
#define NCOMP 24
#define NBETA 10
#define FC 1554
#define NA 32
#define NB 8
#define NOBJ 16384
#define VD (NV*3)          // 2334
#define BCH 584            // ceil(VD/4) row-chunks per batch for k_blend
#define NVQ 832            // padded vertex slots (104 groups of 8)
#define NG 104             // NVQ/8 groups
#define NCB 132            // extra C-blocks (528 outputs, one WAVE each)
#define VSL 25             // verts per skel slice (32*25 >= 778)
#define FSL 49             // faces per face slice (32*49 >= 1554)
#define ZSL 73             // NRM zero-slice (32*73 >= 2334)

// ---------------- Kernel 1: fused pose + blendshapes + C0/C1 side-compute.
__global__ __launch_bounds__(256) void k_blend(
    const float* __restrict__ hp, const float* __restrict__ pca,
    const float* __restrict__ vt, const float* __restrict__ sd,
    const float* __restrict__ pd, const float* __restrict__ beta,
    const float* __restrict__ Jreg,
    float* __restrict__ VP, float* __restrict__ C0, float* __restrict__ C1,
    float* __restrict__ pen)
{
    int bid = blockIdx.x;
    int t = threadIdx.x;
    int wid = t >> 6, lane = t & 63;

    if (bid >= NB*BCH) {               // ---- C-blocks: one wave per output
        int o = (bid - NB*BCH)*4 + wid;          // 0..527
        if (o < 528) {
            int jd, k;
            if (o < 48) { jd = o; k = -1; }
            else        { jd = (o-48)/NBETA; k = (o-48)%NBETA; }
            int j = jd/3, d = jd%3;
            const float* jr = Jreg + j*NV;
            float acc = 0.0f;
            for (int v = lane; v < NV; v += 64) {
                float x = (k < 0) ? vt[v*3+d] : sd[(v*3+d)*NBETA + k];
                acc += jr[v] * x;
            }
            #pragma unroll
            for (int off = 32; off; off >>= 1) acc += __shfl_down(acc, off, 64);
            if (lane == 0) { if (k < 0) C0[jd] = acc; else C1[jd*NBETA + k] = acc; }
        }
        return;
    }

    int b = bid / BCH, c = bid % BCH;
    __shared__ float h45[45];
    __shared__ float sR[NJ*9];
    __shared__ float spf[135];

    if (t < 45) {
        float acc = 0.0f;
        #pragma unroll
        for (int k = 0; k < NCOMP; ++k) acc += hp[b*30 + 6 + k] * pca[k*45 + t];
        h45[t] = acc;
    }
    __syncthreads();
    if (t < NJ) {
        float rx, ry, rz;
        if (t == 0) { rx = hp[b*30+3]; ry = hp[b*30+4]; rz = hp[b*30+5]; }
        else        { rx = h45[(t-1)*3]; ry = h45[(t-1)*3+1]; rz = h45[(t-1)*3+2]; }
        float th = sqrtf(rx*rx + ry*ry + rz*rz + 1e-16f);
        float kx = rx/th, ky = ry/th, kz = rz/th;
        float cc = cosf(th), s = sinf(th), o = 1.0f - cc;
        float R[9];
        R[0] = cc + o*kx*kx;     R[1] = -s*kz + o*kx*ky;  R[2] =  s*ky + o*kx*kz;
        R[3] =  s*kz + o*ky*kx;  R[4] = cc + o*ky*ky;     R[5] = -s*kx + o*ky*kz;
        R[6] = -s*ky + o*kz*kx;  R[7] =  s*kx + o*kz*ky;  R[8] = cc + o*kz*kz;
        #pragma unroll
        for (int i = 0; i < 9; ++i) sR[t*9+i] = R[i];
    }
    __syncthreads();
    if (t < 135) {
        int mn = t % 9;
        float d = (mn == 0 || mn == 4 || mn == 8) ? 1.0f : 0.0f;
        spf[t] = sR[9 + t] - d;
    }
    if (bid == 0 && t == 0) *pen = 0.0f;
    __syncthreads();

    int r = c*4 + wid;                 // row within batch: v*3 + d
    if (r < VD) {
        const float* p  = pd + r * 135;
        float accP = p[lane] * spf[lane] + p[lane+64] * spf[lane+64];
        accP += (lane < 7) ? p[lane+128] * spf[lane+128] : 0.0f;

        float accS = (lane < NBETA) ? sd[r*NBETA + lane] * beta[b*NBETA + lane] : 0.0f;

        #pragma unroll
        for (int off = 32; off; off >>= 1) {
            accP += __shfl_down(accP, off, 64);
            accS += __shfl_down(accS, off, 64);
        }
        if (lane == 0) VP[b*VD + r] = vt[r] + accS + accP;
    }
}

// ---------------- Kernel 2: SLICED skeleton — chip does each batch's LBS once.
// 256 blocks (32 slices/batch). Pose+chain redone per block (tiny, hidden);
// each block LBS-computes 25 verts -> PK/verts, zeroes its NRM slice.
__global__ __launch_bounds__(256) void k_skelp(
    const float* __restrict__ hp, const float* __restrict__ pca,
    const float* __restrict__ beta,
    const float* __restrict__ C0, const float* __restrict__ C1,
    const float* __restrict__ W, const float* __restrict__ VP,
    float* __restrict__ verts, float4* __restrict__ PK, float* __restrict__ NRM)
{
    int k = blockIdx.x;
    int b = k >> 5, s = k & 31;
    int t = threadIdx.x;
    __shared__ float h45[45];
    __shared__ float sR[NJ*9];
    __shared__ float sJ[NJ*3];
    __shared__ float4 sA4[NJ*3];

    // PCA matvec + NRM zero-slice + PK sentinels
    if (t < 45) {
        float acc = 0.0f;
        #pragma unroll
        for (int kk = 0; kk < NCOMP; ++kk) acc += hp[b*30 + 6 + kk] * pca[kk*45 + t];
        h45[t] = acc;
    }
    {
        int zi = s*ZSL + (t - 128);
        if (t >= 128 && t < 128 + ZSL && zi - s*ZSL + s*ZSL < VD && zi < VD) NRM[b*VD + zi] = 0.0f;
    }
    if (s == 0 && t >= 192 && t < 192 + (NVQ - NV))
        PK[b*NVQ + NV + (t - 192)] = make_float4(0.f, 0.f, 0.f, 1e30f);
    __syncthreads();

    // Rodrigues (t<16) + joints from C0/C1 (t in 64..112)
    if (t < NJ) {
        float rx, ry, rz;
        if (t == 0) { rx = hp[b*30+3]; ry = hp[b*30+4]; rz = hp[b*30+5]; }
        else        { rx = h45[(t-1)*3]; ry = h45[(t-1)*3+1]; rz = h45[(t-1)*3+2]; }
        float th = sqrtf(rx*rx + ry*ry + rz*rz + 1e-16f);
        float kx = rx/th, ky = ry/th, kz = rz/th;
        float cc = cosf(th), sn_ = sinf(th), o = 1.0f - cc;
        sR[t*9+0] = cc + o*kx*kx;      sR[t*9+1] = -sn_*kz + o*kx*ky;  sR[t*9+2] =  sn_*ky + o*kx*kz;
        sR[t*9+3] =  sn_*kz + o*ky*kx; sR[t*9+4] = cc + o*ky*ky;       sR[t*9+5] = -sn_*kx + o*ky*kz;
        sR[t*9+6] = -sn_*ky + o*kz*kx; sR[t*9+7] =  sn_*kx + o*kz*ky;  sR[t*9+8] = cc + o*kz*kz;
    }
    if (t >= 64 && t < 64 + NJ*3) {
        int o = t - 64;
        float acc = C0[o];
        #pragma unroll
        for (int kk = 0; kk < NBETA; ++kk) acc += C1[o*NBETA + kk] * beta[b*NBETA + kk];
        sJ[o] = acc;
    }
    __syncthreads();

    // chain (thread m owns row m)
    if (t < 3) {
        const int par[NJ] = {-1,0,1,2,0,4,5,0,7,8,0,10,11,0,13,14};
        int m = t;
        float Tr[NJ][3], Tt[NJ];
        Tr[0][0] = sR[m*3+0]; Tr[0][1] = sR[m*3+1]; Tr[0][2] = sR[m*3+2];
        Tt[0] = sJ[m];
        #pragma unroll
        for (int j = 1; j < NJ; ++j) {
            int p = par[j];
            float t0 = sJ[j*3+0] - sJ[p*3+0];
            float t1 = sJ[j*3+1] - sJ[p*3+1];
            float t2 = sJ[j*3+2] - sJ[p*3+2];
            float a0 = Tr[p][0], a1 = Tr[p][1], a2 = Tr[p][2];
            #pragma unroll
            for (int n = 0; n < 3; ++n)
                Tr[j][n] = a0*sR[j*9+n] + a1*sR[j*9+3+n] + a2*sR[j*9+6+n];
            Tt[j] = a0*t0 + a1*t1 + a2*t2 + Tt[p];
        }
        #pragma unroll
        for (int j = 0; j < NJ; ++j) {
            float corr = Tr[j][0]*sJ[j*3] + Tr[j][1]*sJ[j*3+1] + Tr[j][2]*sJ[j*3+2];
            sA4[j*3 + m] = make_float4(Tr[j][0], Tr[j][1], Tr[j][2], Tt[j] - corr);
        }
    }
    __syncthreads();

    // LBS slice: t<25, vertex v = s*25 + t
    if (t < VSL) {
        int v = s*VSL + t;
        if (v < NV) {
            float4 r0 = make_float4(0,0,0,0), r1 = make_float4(0,0,0,0), r2 = make_float4(0,0,0,0);
            const float4* w4 = (const float4*)(W + v * NJ);
            #pragma unroll
            for (int q = 0; q < 4; ++q) {
                float4 wv = w4[q];
                #pragma unroll
                for (int jj = 0; jj < 4; ++jj) {
                    int j = q*4 + jj;
                    float wj = (jj==0)?wv.x:(jj==1)?wv.y:(jj==2)?wv.z:wv.w;
                    float4 A0 = sA4[j*3+0], A1 = sA4[j*3+1], A2 = sA4[j*3+2];
                    r0.x += wj*A0.x; r0.y += wj*A0.y; r0.z += wj*A0.z; r0.w += wj*A0.w;
                    r1.x += wj*A1.x; r1.y += wj*A1.y; r1.z += wj*A1.z; r1.w += wj*A1.w;
                    r2.x += wj*A2.x; r2.y += wj*A2.y; r2.z += wj*A2.z; r2.w += wj*A2.w;
                }
            }
            float tx = hp[b*30+0], ty = hp[b*30+1], tz = hp[b*30+2];
            float px = VP[b*VD + v*3], py = VP[b*VD + v*3+1], pz = VP[b*VD + v*3+2];
            float x = r0.x*px + r0.y*py + r0.z*pz + r0.w + tx;
            float y = r1.x*px + r1.y*py + r1.z*pz + r1.w + ty;
            float z = r2.x*px + r2.y*py + r2.z*pz + r2.w + tz;
            int i = b*NV + v;
            verts[i*3] = x; verts[i*3+1] = y; verts[i*3+2] = z;
            PK[b*NVQ + v] = make_float4(x, y, z, 0.5f*(x*x + y*y + z*z));
        }
    }
}

// ---------------- Kernel 3: sliced face normals (global atomics) + contact.
__global__ __launch_bounds__(256) void k_faces(
    const int* __restrict__ faces, const float4* __restrict__ PK,
    const float* __restrict__ aw, const int* __restrict__ afi,
    float* __restrict__ NRM, float* __restrict__ contact)
{
    int k = blockIdx.x;
    int b = k >> 5, s = k & 31;
    int t = threadIdx.x;

    if (t < FSL) {
        int f = s*FSL + t;
        if (f < FC) {
            int i0 = faces[f*3], i1 = faces[f*3+1], i2 = faces[f*3+2];
            float4 p0 = PK[b*NVQ + i0];
            float4 p1 = PK[b*NVQ + i1];
            float4 p2 = PK[b*NVQ + i2];
            float ax = p1.x-p0.x, ay = p1.y-p0.y, az = p1.z-p0.z;
            float bx = p2.x-p0.x, by = p2.y-p0.y, bz = p2.z-p0.z;
            float cx = ay*bz - az*by, cy = az*bx - ax*bz, cz = ax*by - ay*bx;
            float* nb = NRM + b*VD;
            atomicAdd(nb + i0*3+0, cx); atomicAdd(nb + i0*3+1, cy); atomicAdd(nb + i0*3+2, cz);
            atomicAdd(nb + i1*3+0, cx); atomicAdd(nb + i1*3+1, cy); atomicAdd(nb + i1*3+2, cz);
            atomicAdd(nb + i2*3+0, cx); atomicAdd(nb + i2*3+1, cy); atomicAdd(nb + i2*3+2, cz);
        }
    }
    if (s == 0 && t >= 64 && t < 64 + NA*3) {
        int a = (t-64) / 3, d = (t-64) % 3;
        float acc = 0.0f;
        #pragma unroll
        for (int kk = 0; kk < 3; ++kk) {
            const float* pv = (const float*)(PK + b*NVQ + afi[a*3 + kk]);
            acc += aw[a*3 + kk] * pv[d];
        }
        contact[b*NA*3 + t - 64] = acc;
    }
}

// one vertex vs both points; ascending vidx + strict < == jnp.argmin first-index
#define PROC1(vk, vidx) {                                                        \
    float d0 = fmaf(-ox0, (vk).x, (vk).w);                                       \
    d0 = fmaf(-oy0, (vk).y, d0); d0 = fmaf(-oz0, (vk).z, d0);                    \
    if (d0 < s0) { s0 = d0; j0 = (vidx); }                                       \
    float d1 = fmaf(-ox1, (vk).x, (vk).w);                                       \
    d1 = fmaf(-oy1, (vk).y, d1); d1 = fmaf(-oz1, (vk).z, d1);                    \
    if (d1 < s1) { s1 = d1; j1 = (vidx); } }

#define PROC8(buf, gbase) {                                                      \
    PROC1((buf)[0], (gbase)+0); PROC1((buf)[1], (gbase)+1);                      \
    PROC1((buf)[2], (gbase)+2); PROC1((buf)[3], (gbase)+3);                      \
    PROC1((buf)[4], (gbase)+4); PROC1((buf)[5], (gbase)+5);                      \
    PROC1((buf)[6], (gbase)+6); PROC1((buf)[7], (gbase)+7); }

// ---------------- Kernel 4: NN search (R7 ping-pong), sPK + sNRM staged.
__global__ __launch_bounds__(256) void k_nn(const float* __restrict__ obj,
                                            const float4* __restrict__ PK,
                                            const float* __restrict__ NRM,
                                            float* __restrict__ cmap,
                                            float* __restrict__ pen)
{
    int blk = blockIdx.x;
    int b = blk >> 5;                 // batch
    int g = blk & 31;                 // point-group within batch
    int t = threadIdx.x, lane = t & 63, wid = t >> 6;

    __shared__ float4 sPK[NVQ];
    __shared__ float sNRM[VD];
    __shared__ float wsum[4];

    int n0 = g*512 + t;
    int n1 = n0 + 256;
    const float* o0p = obj + (b*NOBJ + n0)*3;
    const float* o1p = obj + (b*NOBJ + n1)*3;
    float ox0 = o0p[0], oy0 = o0p[1], oz0 = o0p[2];
    float ox1 = o1p[0], oy1 = o1p[1], oz1 = o1p[2];

    for (int i = t; i < NVQ; i += 256) sPK[i] = PK[b*NVQ + i];
    for (int i = t; i < VD; i += 256) sNRM[i] = NRM[b*VD + i];
    __syncthreads();

    float s0 = 1e30f, s1 = 1e30f;
    int j0 = 0, j1 = 0;
    {
        float4 A[8], B[8];
        #pragma unroll
        for (int k = 0; k < 8; ++k) A[k] = sPK[k];           // prologue: group 0
        for (int gg = 0; gg + 2 <= NG; gg += 2) {
            #pragma unroll
            for (int k = 0; k < 8; ++k) B[k] = sPK[(gg+1)*8 + k];  // issue g+1
            PROC8(A, gg*8);                                         // compute g
            if (gg + 2 < NG) {
                #pragma unroll
                for (int k = 0; k < 8; ++k) A[k] = sPK[(gg+2)*8 + k];  // issue g+2
            }
            PROC8(B, (gg+1)*8);                                     // compute g+1
        }
    }

    float osq0 = ox0*ox0 + oy0*oy0 + oz0*oz0;
    float d20 = 2.0f * s0 + osq0;
    cmap[b*NOBJ + n0] = 2.0f / (1.0f + __expf(100.0f * d20));
    float4 q0 = sPK[j0];
    float dp0 = (q0.x - ox0)*sNRM[j0*3+0] + (q0.y - oy0)*sNRM[j0*3+1]
              + (q0.z - oz0)*sNRM[j0*3+2];
    float p = (dp0 > 0.0f) ? d20 : 0.0f;

    float osq1 = ox1*ox1 + oy1*oy1 + oz1*oz1;
    float d21 = 2.0f * s1 + osq1;
    cmap[b*NOBJ + n1] = 2.0f / (1.0f + __expf(100.0f * d21));
    float4 q1 = sPK[j1];
    float dp1 = (q1.x - ox1)*sNRM[j1*3+0] + (q1.y - oy1)*sNRM[j1*3+1]
              + (q1.z - oz1)*sNRM[j1*3+2];
    p += (dp1 > 0.0f) ? d21 : 0.0f;

    for (int off = 32; off; off >>= 1) p += __shfl_down(p, off, 64);
    if (lane == 0) wsum[wid] = p;
    __syncthreads();
    if (t == 0) atomicAdd(pen, (wsum[0] + wsum[1] + wsum[2] + wsum[3]) * (1.0f / NB));
}

extern "C" void kernel_launch(void* const* d_in, const int* in_sizes, int n_in,
                              void* d_out, int out_size, void* d_ws, size_t ws_size,
                              hipStream_t stream)
{
    const float* hp    = (const float*)d_in[0];
    const float* obj   = (const float*)d_in[1];
    const float* beta  = (const float*)d_in[2];
    const float* vt    = (const float*)d_in[3];
    const float* sd    = (const float*)d_in[4];
    const float* pd    = (const float*)d_in[5];
    const float* Jreg  = (const float*)d_in[6];
    const float* W     = (const float*)d_in[7];
    const float* pca   = (const float*)d_in[8];
    const float* aw    = (const float*)d_in[9];
    const int*   faces = (const int*)d_in[10];
    const int*   afi   = (const int*)d_in[11];

    float* out     = (float*)d_out;
    float* cmap    = out;                          // 131072
    float* pen     = out + NB*NOBJ;                // 1
    float* verts   = out + NB*NOBJ + 1;            // 18672
    float* contact = out + NB*NOBJ + 1 + NB*NV*3;  // 768

    float* ws   = (float*)d_ws;
    float4* PK  = (float4*)ws;        // NB*NVQ float4
    float* NRM  = ws + NB*NVQ*4;      // NB*VD
    float* VP   = NRM + NB*VD;        // NB*VD
    float* C0   = VP + NB*VD;         // 48
    float* C1   = C0 + 48;            // 480

    k_blend<<<NB*BCH + NCB, 256, 0, stream>>>(hp, pca, vt, sd, pd, beta, Jreg,
                                              VP, C0, C1, pen);
    k_skelp<<<NB*32, 256, 0, stream>>>(hp, pca, beta, C0, C1, W, VP,
                                       verts, PK, NRM);
    k_faces<<<NB*32, 256, 0, stream>>>(faces, PK, aw, afi, NRM, contact);
    k_nn   <<<NB*32, 256, 0, stream>>>(obj, PK, NRM, cmap, pen);
}